// Round 1
// baseline (992.952 us; speedup 1.0000x reference)
//
#include <hip/hip_runtime.h>
#include <cstddef>

// TwinSAGE: 2-layer GraphSAGE (mean aggr) + twin query path + 2-way layer
// attention + output projection. Round 1: all-fp32 correctness baseline.
//
// Sizes (fixed by the problem):
//   N0=500000, N1=100000, B=10000, E0=1e6, E1=1e5, F_IN=128, HID=256, C=40

namespace {

constexpr int N1i  = 100000;
constexpr int Bni  = 10000;
constexpr int E0i  = 1000000;
constexpr int E1i  = 100000;
constexpr int FIN  = 128;
constexpr int HID  = 256;
constexpr int NCLS = 40;

// ---------------- CSR build ----------------

__global__ void hist_kernel(const int* __restrict__ dst, int n, int* __restrict__ cnt) {
    int i = blockIdx.x * blockDim.x + threadIdx.x;
    if (i < n) atomicAdd(&cnt[dst[i]], 1);
}

__global__ void partial_sum_kernel(const int* __restrict__ cnt, int n, int* __restrict__ bsum) {
    __shared__ int s[256];
    int i = blockIdx.x * 256 + threadIdx.x;
    s[threadIdx.x] = (i < n) ? cnt[i] : 0;
    __syncthreads();
    for (int o = 128; o > 0; o >>= 1) {
        if (threadIdx.x < o) s[threadIdx.x] += s[threadIdx.x + o];
        __syncthreads();
    }
    if (threadIdx.x == 0) bsum[blockIdx.x] = s[0];
}

__global__ void scan_bsum_kernel(int* __restrict__ bsum, int nb, int* __restrict__ total_out) {
    if (threadIdx.x == 0 && blockIdx.x == 0) {
        int acc = 0;
        for (int i = 0; i < nb; i++) { int t = bsum[i]; bsum[i] = acc; acc += t; }
        *total_out = acc;
    }
}

__global__ void scan_final_kernel(const int* __restrict__ cnt, int n,
                                  const int* __restrict__ bsum, int* __restrict__ row_ptr) {
    __shared__ int s[256];
    int t = threadIdx.x;
    int i = blockIdx.x * 256 + t;
    int v = (i < n) ? cnt[i] : 0;
    s[t] = v;
    __syncthreads();
    // inclusive Hillis-Steele scan
    for (int o = 1; o < 256; o <<= 1) {
        int u = (t >= o) ? s[t - o] : 0;
        __syncthreads();
        s[t] += u;
        __syncthreads();
    }
    if (i < n) row_ptr[i] = bsum[blockIdx.x] + s[t] - v;  // exclusive
}

__global__ void copy_int_kernel(const int* __restrict__ a, int n, int* __restrict__ b) {
    int i = blockIdx.x * blockDim.x + threadIdx.x;
    if (i < n) b[i] = a[i];
}

__global__ void scatter_kernel(const int* __restrict__ src, const int* __restrict__ dst, int n,
                               int* __restrict__ cursor, int* __restrict__ es) {
    int i = blockIdx.x * blockDim.x + threadIdx.x;
    if (i < n) {
        int p = atomicAdd(&cursor[dst[i]], 1);
        es[p] = src[i];
    }
}

// ---------------- Mean aggregation (one wave per target) ----------------

__global__ __launch_bounds__(256) void agg_mean128_kernel(
    const float* __restrict__ x, const int* __restrict__ rp,
    const int* __restrict__ es, float* __restrict__ out, int ntgt) {
    int tgt  = blockIdx.x * 4 + (threadIdx.x >> 6);
    int lane = threadIdx.x & 63;
    if (tgt >= ntgt) return;
    int b = rp[tgt], e = rp[tgt + 1];
    float ax = 0.f, ay = 0.f;
    for (int i = b; i < e; i++) {
        const float2 v = *(const float2*)(x + (size_t)es[i] * FIN + lane * 2);
        ax += v.x; ay += v.y;
    }
    float inv = 1.0f / fmaxf((float)(e - b), 1.0f);
    float2 r; r.x = ax * inv; r.y = ay * inv;
    *(float2*)(out + (size_t)tgt * FIN + lane * 2) = r;
}

__global__ __launch_bounds__(256) void agg_mean256_kernel(
    const float* __restrict__ h, const int* __restrict__ rp,
    const int* __restrict__ es, float* __restrict__ out, int ntgt) {
    int tgt  = blockIdx.x * 4 + (threadIdx.x >> 6);
    int lane = threadIdx.x & 63;
    if (tgt >= ntgt) return;
    int b = rp[tgt], e = rp[tgt + 1];
    float4 acc = {0.f, 0.f, 0.f, 0.f};
    for (int i = b; i < e; i++) {
        const float4 v = *(const float4*)(h + (size_t)es[i] * HID + lane * 4);
        acc.x += v.x; acc.y += v.y; acc.z += v.z; acc.w += v.w;
    }
    float inv = 1.0f / fmaxf((float)(e - b), 1.0f);
    float4 r; r.x = acc.x * inv; r.y = acc.y * inv; r.z = acc.z * inv; r.w = acc.w * inv;
    *(float4*)(out + (size_t)tgt * HID + lane * 4) = r;
}

// ---------------- fp32 tiled GEMM: C = act(A1@B1 + A2@B2 + bias) ----------------
// A1: M x K1 (row-major, stride K1), A2: M x K2, B1: K1 x 256, B2: K2 x 256.
// 64x64 tile, BK=16, 256 threads, 4x4 per thread.

template <int K1, int K2, bool RELU>
__global__ __launch_bounds__(256) void gemm_kernel(
    const float* __restrict__ A1, const float* __restrict__ A2,
    const float* __restrict__ B1, const float* __restrict__ B2,
    const float* __restrict__ bias, float* __restrict__ C, int M) {
    constexpr int N  = 256;
    constexpr int BK = 16;
    __shared__ __align__(16) float As[BK][68];  // +4 pad: 16B-aligned rows, conflict-light
    __shared__ __align__(16) float Bs[BK][68];
    const int tid  = threadIdx.x;
    const int m0   = blockIdx.x * 64;
    const int n0   = blockIdx.y * 64;
    const int tn   = (tid & 15) * 4;
    const int tm   = (tid >> 4) * 4;
    const int la_m = tid >> 2;
    const int la_k = (tid & 3) * 4;
    const int lb_k = tid >> 4;
    const int lb_n = (tid & 15) * 4;
    float c[4][4] = {};

    for (int k0 = 0; k0 < K1 + K2; k0 += BK) {
        const float* Ap; const float* Bp; int kk, lda;
        if (k0 < K1) { Ap = A1; Bp = B1; kk = k0;      lda = K1; }
        else         { Ap = A2; Bp = B2; kk = k0 - K1; lda = K2; }
        int mrow = m0 + la_m;
        if (mrow >= M) mrow = M - 1;  // clamp: duplicate last row, store is guarded
        float4 av = *(const float4*)(Ap + (size_t)mrow * lda + (kk + la_k));
        float4 bv = *(const float4*)(Bp + (size_t)(kk + lb_k) * N + (n0 + lb_n));
        __syncthreads();
        As[la_k + 0][la_m] = av.x; As[la_k + 1][la_m] = av.y;
        As[la_k + 2][la_m] = av.z; As[la_k + 3][la_m] = av.w;
        *(float4*)&Bs[lb_k][lb_n] = bv;
        __syncthreads();
#pragma unroll
        for (int k = 0; k < BK; k++) {
            const float4 a = *(const float4*)&As[k][tm];
            const float4 b = *(const float4*)&Bs[k][tn];
            c[0][0] += a.x * b.x; c[0][1] += a.x * b.y; c[0][2] += a.x * b.z; c[0][3] += a.x * b.w;
            c[1][0] += a.y * b.x; c[1][1] += a.y * b.y; c[1][2] += a.y * b.z; c[1][3] += a.y * b.w;
            c[2][0] += a.z * b.x; c[2][1] += a.z * b.y; c[2][2] += a.z * b.z; c[2][3] += a.z * b.w;
            c[3][0] += a.w * b.x; c[3][1] += a.w * b.y; c[3][2] += a.w * b.z; c[3][3] += a.w * b.w;
        }
    }

    float bj[4] = {0.f, 0.f, 0.f, 0.f};
    if (bias) {
        bj[0] = bias[n0 + tn + 0]; bj[1] = bias[n0 + tn + 1];
        bj[2] = bias[n0 + tn + 2]; bj[3] = bias[n0 + tn + 3];
    }
#pragma unroll
    for (int i = 0; i < 4; i++) {
        int mrow = m0 + tm + i;
        if (mrow >= M) break;
        float4 r;
        r.x = c[i][0] + bj[0]; r.y = c[i][1] + bj[1];
        r.z = c[i][2] + bj[2]; r.w = c[i][3] + bj[3];
        if (RELU) {
            r.x = fmaxf(r.x, 0.f); r.y = fmaxf(r.y, 0.f);
            r.z = fmaxf(r.z, 0.f); r.w = fmaxf(r.w, 0.f);
        }
        *(float4*)(C + (size_t)mrow * N + n0 + tn) = r;
    }
}

// ---------------- Fused attention + output projection ----------------
// Per row i: s0=dot(h[i],q1[i]), s1=dot(h2[i],q2[i]); softmax over {s0,s1};
// c = a0*h[i] + a1*h2[i]; out[i] = c @ Wout + bout.

__global__ __launch_bounds__(256) void attn_out_kernel(
    const float* __restrict__ h, const float* __restrict__ h2,
    const float* __restrict__ q1, const float* __restrict__ q2,
    const float* __restrict__ Wout, const float* __restrict__ bout,
    float* __restrict__ out, int Bn) {
    int w = threadIdx.x >> 6, lane = threadIdx.x & 63;
    int row = blockIdx.x * 4 + w;
    __shared__ __align__(16) float cbuf[4][260];
    if (row < Bn) {
        const float4 a = *(const float4*)(h  + (size_t)row * HID + lane * 4);
        const float4 p = *(const float4*)(q1 + (size_t)row * HID + lane * 4);
        const float4 b = *(const float4*)(h2 + (size_t)row * HID + lane * 4);
        const float4 q = *(const float4*)(q2 + (size_t)row * HID + lane * 4);
        float s0 = a.x * p.x + a.y * p.y + a.z * p.z + a.w * p.w;
        float s1 = b.x * q.x + b.y * q.y + b.z * q.z + b.w * q.w;
        for (int o = 32; o > 0; o >>= 1) {
            s0 += __shfl_xor(s0, o);
            s1 += __shfl_xor(s1, o);
        }
        float m  = fmaxf(s0, s1);
        float e0 = __expf(s0 - m), e1 = __expf(s1 - m);
        float inv = 1.0f / (e0 + e1);
        float a0 = e0 * inv, a1 = e1 * inv;
        float4 cv;
        cv.x = a0 * a.x + a1 * b.x; cv.y = a0 * a.y + a1 * b.y;
        cv.z = a0 * a.z + a1 * b.z; cv.w = a0 * a.w + a1 * b.w;
        *(float4*)&cbuf[w][lane * 4] = cv;
    }
    __syncthreads();
    int t = threadIdx.x;
    if (t < 4 * NCLS) {
        int r = t / NCLS, j = t % NCLS;
        int orow = blockIdx.x * 4 + r;
        if (orow < Bn) {
            float acc = bout[j];
#pragma unroll 8
            for (int k = 0; k < HID; k++) acc += cbuf[r][k] * Wout[k * NCLS + j];
            out[(size_t)orow * NCLS + j] = acc;
        }
    }
}

}  // namespace

extern "C" void kernel_launch(void* const* d_in, const int* in_sizes, int n_in,
                              void* d_out, int out_size, void* d_ws, size_t ws_size,
                              hipStream_t stream) {
    const float* x    = (const float*)d_in[0];
    const int*   src0 = (const int*)d_in[1];
    const int*   dst0 = (const int*)d_in[2];
    const int*   src1 = (const int*)d_in[3];
    const int*   dst1 = (const int*)d_in[4];
    const float* W1l  = (const float*)d_in[5];
    const float* b1   = (const float*)d_in[6];
    const float* W1r  = (const float*)d_in[7];
    const float* W2l  = (const float*)d_in[8];
    const float* b2   = (const float*)d_in[9];
    const float* W2r  = (const float*)d_in[10];
    const float* Wout = (const float*)d_in[11];
    const float* bout = (const float*)d_in[12];
    float* out = (float*)d_out;

    // ---- workspace carve-up (all offsets 256B-aligned) ----
    char* ws = (char*)d_ws;
    size_t off = 0;
    auto alloc = [&](size_t bytes) {
        void* p = ws + off;
        off = (off + bytes + 255) & ~(size_t)255;
        return p;
    };
    int* cnt0  = (int*)alloc(N1i * sizeof(int));        // counts, then scatter cursor
    int* rp0   = (int*)alloc((N1i + 1) * sizeof(int));
    int* bsum0 = (int*)alloc(512 * sizeof(int));
    int* es0   = (int*)alloc(E0i * sizeof(int));        // src sorted by dst
    int* cnt1  = (int*)alloc(Bni * sizeof(int));
    int* rp1   = (int*)alloc((Bni + 1) * sizeof(int));
    int* bsum1 = (int*)alloc(512 * sizeof(int));
    int* es1   = (int*)alloc(E1i * sizeof(int));
    // agg region: holds agg0 (N1 x 128) during layer 1; reused afterwards for
    // the four B x 256 buffers (4 * 2.56M floats < 12.8M floats).
    float* region = (float*)alloc((size_t)N1i * FIN * sizeof(float));
    float* h      = (float*)alloc((size_t)N1i * HID * sizeof(float));
    float* agg0 = region;
    float* hq1  = region;                               // after GEMM1, agg0 is dead
    float* agg1 = region + (size_t)1 * Bni * HID;
    float* h2   = region + (size_t)2 * Bni * HID;
    float* h2q  = region + (size_t)3 * Bni * HID;

    // ---- CSR build: graph0 (E0 -> N1) and graph1 (E1 -> B) ----
    hipMemsetAsync(cnt0, 0, N1i * sizeof(int), stream);
    hipMemsetAsync(cnt1, 0, Bni * sizeof(int), stream);
    hist_kernel<<<(E0i + 255) / 256, 256, 0, stream>>>(dst0, E0i, cnt0);
    hist_kernel<<<(E1i + 255) / 256, 256, 0, stream>>>(dst1, E1i, cnt1);

    int nb0 = (N1i + 255) / 256, nb1 = (Bni + 255) / 256;
    partial_sum_kernel<<<nb0, 256, 0, stream>>>(cnt0, N1i, bsum0);
    scan_bsum_kernel<<<1, 64, 0, stream>>>(bsum0, nb0, rp0 + N1i);
    scan_final_kernel<<<nb0, 256, 0, stream>>>(cnt0, N1i, bsum0, rp0);
    copy_int_kernel<<<(N1i + 255) / 256, 256, 0, stream>>>(rp0, N1i, cnt0);
    scatter_kernel<<<(E0i + 255) / 256, 256, 0, stream>>>(src0, dst0, E0i, cnt0, es0);

    partial_sum_kernel<<<nb1, 256, 0, stream>>>(cnt1, Bni, bsum1);
    scan_bsum_kernel<<<1, 64, 0, stream>>>(bsum1, nb1, rp1 + Bni);
    scan_final_kernel<<<nb1, 256, 0, stream>>>(cnt1, Bni, bsum1, rp1);
    copy_int_kernel<<<(Bni + 255) / 256, 256, 0, stream>>>(rp1, Bni, cnt1);
    scatter_kernel<<<(E1i + 255) / 256, 256, 0, stream>>>(src1, dst1, E1i, cnt1, es1);

    // ---- layer 1 ----
    agg_mean128_kernel<<<(N1i + 3) / 4, 256, 0, stream>>>(x, rp0, es0, agg0, N1i);
    {
        dim3 g((N1i + 63) / 64, HID / 64);
        // h = relu(agg0 @ W1l + x[:N1] @ W1r + b1)
        gemm_kernel<128, 128, true><<<g, 256, 0, stream>>>(agg0, x, W1l, W1r, b1, h, N1i);
    }
    {
        dim3 g((Bni + 63) / 64, HID / 64);
        // hq1 = relu(x[:B] @ W1r)   (overwrites agg0 region: agg0 is dead now)
        gemm_kernel<128, 0, true><<<g, 256, 0, stream>>>(x, nullptr, W1r, nullptr, nullptr, hq1, Bni);
    }

    // ---- layer 2 ----
    agg_mean256_kernel<<<(Bni + 3) / 4, 256, 0, stream>>>(h, rp1, es1, agg1, Bni);
    {
        dim3 g((Bni + 63) / 64, HID / 64);
        // h2 = relu(agg1 @ W2l + h[:B] @ W2r + b2)
        gemm_kernel<256, 256, true><<<g, 256, 0, stream>>>(agg1, h, W2l, W2r, b2, h2, Bni);
        // h2q = relu(hq1 @ W2r)
        gemm_kernel<256, 0, true><<<g, 256, 0, stream>>>(hq1, nullptr, W2r, nullptr, nullptr, h2q, Bni);
    }

    // ---- attention + output projection ----
    attn_out_kernel<<<(Bni + 3) / 4, 256, 0, stream>>>(h, h2, hq1, h2q, Wout, bout, out, Bni);
}

// Round 2
// 826.783 us; speedup vs baseline: 1.2010x; 1.2010x over previous
//
#include <hip/hip_runtime.h>
#include <cstddef>

// TwinSAGE: 2-layer GraphSAGE (mean aggr) + twin query path + 2-way layer
// attention + output projection.
// Round 2: split-bf16 (hi+lo, 3-term) MFMA GEMMs + parallel block-sum scan.

namespace {

constexpr int N1i  = 100000;
constexpr int Bni  = 10000;
constexpr int E0i  = 1000000;
constexpr int E1i  = 100000;
constexpr int FIN  = 128;
constexpr int HID  = 256;
constexpr int NCLS = 40;

typedef __attribute__((ext_vector_type(8))) short short8;
typedef __attribute__((ext_vector_type(8))) unsigned short ushort8;
typedef __attribute__((ext_vector_type(4))) float floatx4;

// ---------------- CSR build ----------------

__global__ void hist_kernel(const int* __restrict__ dst, int n, int* __restrict__ cnt) {
    int i = blockIdx.x * blockDim.x + threadIdx.x;
    if (i < n) atomicAdd(&cnt[dst[i]], 1);
}

__global__ void partial_sum_kernel(const int* __restrict__ cnt, int n, int* __restrict__ bsum) {
    __shared__ int s[256];
    int i = blockIdx.x * 256 + threadIdx.x;
    s[threadIdx.x] = (i < n) ? cnt[i] : 0;
    __syncthreads();
    for (int o = 128; o > 0; o >>= 1) {
        if (threadIdx.x < o) s[threadIdx.x] += s[threadIdx.x + o];
        __syncthreads();
    }
    if (threadIdx.x == 0) bsum[blockIdx.x] = s[0];
}

// Parallel single-block exclusive scan of bsum (nb <= 512).
// Replaces the serial 1-thread loop (391 dependent global round-trips ~115us).
__global__ void scan_bsum_par_kernel(int* __restrict__ bsum, int nb, int* __restrict__ total_out) {
    __shared__ int s[512];
    int t = threadIdx.x;
    int v = (t < nb) ? bsum[t] : 0;
    s[t] = v;
    __syncthreads();
    for (int o = 1; o < 512; o <<= 1) {
        int u = (t >= o) ? s[t - o] : 0;
        __syncthreads();
        s[t] += u;
        __syncthreads();
    }
    if (t < nb) bsum[t] = s[t] - v;   // exclusive
    if (t == 511) *total_out = s[511];
}

__global__ void scan_final_kernel(const int* __restrict__ cnt, int n,
                                  const int* __restrict__ bsum, int* __restrict__ row_ptr) {
    __shared__ int s[256];
    int t = threadIdx.x;
    int i = blockIdx.x * 256 + t;
    int v = (i < n) ? cnt[i] : 0;
    s[t] = v;
    __syncthreads();
    for (int o = 1; o < 256; o <<= 1) {
        int u = (t >= o) ? s[t - o] : 0;
        __syncthreads();
        s[t] += u;
        __syncthreads();
    }
    if (i < n) row_ptr[i] = bsum[blockIdx.x] + s[t] - v;  // exclusive
}

__global__ void copy_int_kernel(const int* __restrict__ a, int n, int* __restrict__ b) {
    int i = blockIdx.x * blockDim.x + threadIdx.x;
    if (i < n) b[i] = a[i];
}

__global__ void scatter_kernel(const int* __restrict__ src, const int* __restrict__ dst, int n,
                               int* __restrict__ cursor, int* __restrict__ es) {
    int i = blockIdx.x * blockDim.x + threadIdx.x;
    if (i < n) {
        int p = atomicAdd(&cursor[dst[i]], 1);
        es[p] = src[i];
    }
}

// ---------------- Mean aggregation (one wave per target) ----------------

__global__ __launch_bounds__(256) void agg_mean128_kernel(
    const float* __restrict__ x, const int* __restrict__ rp,
    const int* __restrict__ es, float* __restrict__ out, int ntgt) {
    int tgt  = blockIdx.x * 4 + (threadIdx.x >> 6);
    int lane = threadIdx.x & 63;
    if (tgt >= ntgt) return;
    int b = rp[tgt], e = rp[tgt + 1];
    float ax = 0.f, ay = 0.f;
    for (int i = b; i < e; i++) {
        const float2 v = *(const float2*)(x + (size_t)es[i] * FIN + lane * 2);
        ax += v.x; ay += v.y;
    }
    float inv = 1.0f / fmaxf((float)(e - b), 1.0f);
    float2 r; r.x = ax * inv; r.y = ay * inv;
    *(float2*)(out + (size_t)tgt * FIN + lane * 2) = r;
}

__global__ __launch_bounds__(256) void agg_mean256_kernel(
    const float* __restrict__ h, const int* __restrict__ rp,
    const int* __restrict__ es, float* __restrict__ out, int ntgt) {
    int tgt  = blockIdx.x * 4 + (threadIdx.x >> 6);
    int lane = threadIdx.x & 63;
    if (tgt >= ntgt) return;
    int b = rp[tgt], e = rp[tgt + 1];
    float4 acc = {0.f, 0.f, 0.f, 0.f};
    for (int i = b; i < e; i++) {
        const float4 v = *(const float4*)(h + (size_t)es[i] * HID + lane * 4);
        acc.x += v.x; acc.y += v.y; acc.z += v.z; acc.w += v.w;
    }
    float inv = 1.0f / fmaxf((float)(e - b), 1.0f);
    float4 r; r.x = acc.x * inv; r.y = acc.y * inv; r.z = acc.z * inv; r.w = acc.w * inv;
    *(float4*)(out + (size_t)tgt * HID + lane * 4) = r;
}

// ---------------- weight transpose + bf16 hi/lo split ----------------
// W: K x 256 fp32 (row-major) -> hiT/loT: 256 x K bf16 (ushort payload).

__device__ inline unsigned short bf16_rne_u(unsigned u) {
    unsigned r = u + 0x7fffu + ((u >> 16) & 1u);
    return (unsigned short)(r >> 16);
}

__global__ void wtrans_kernel(const float* __restrict__ W, int K,
                              unsigned short* __restrict__ hiT,
                              unsigned short* __restrict__ loT) {
    int e = blockIdx.x * blockDim.x + threadIdx.x;
    if (e >= K * 256) return;
    int k = e >> 8, n = e & 255;
    float f = W[e];
    unsigned short hs = bf16_rne_u(__float_as_uint(f));
    float lo = f - __uint_as_float((unsigned)hs << 16);
    unsigned short ls = bf16_rne_u(__float_as_uint(lo));
    hiT[n * K + k] = hs;
    loT[n * K + k] = ls;
}

// ---------------- split-bf16 MFMA GEMM ----------------
// C[M x 256] = act(A1@B1 + A2@B2 + bias), A fp32 row-major (stride = K),
// B pre-split/transposed bf16 hi/lo [256][K].
// 3-term split: Ahi*Bhi + Ahi*Blo + Alo*Bhi (error ~2^-17 rel).
// Block 128x128, 4 waves, wave = 4x4 tiles of mfma_f32_16x16x32_bf16, BK=32.

__device__ inline void cvt_store8(unsigned short* hi_dst, unsigned short* lo_dst,
                                  const float* v) {
    ushort8 h, l;
#pragma unroll
    for (int i = 0; i < 8; i++) {
        float f = v[i];
        unsigned short hs = bf16_rne_u(__float_as_uint(f));
        float lo = f - __uint_as_float((unsigned)hs << 16);
        h[i] = hs;
        l[i] = bf16_rne_u(__float_as_uint(lo));
    }
    *(ushort8*)hi_dst = h;
    *(ushort8*)lo_dst = l;
}

template <int K1, int K2, bool RELU>
__global__ __launch_bounds__(256, 2) void gemm_mfma_kernel(
    const float* __restrict__ A1, const float* __restrict__ A2,
    const unsigned short* __restrict__ B1hi, const unsigned short* __restrict__ B1lo,
    const unsigned short* __restrict__ B2hi, const unsigned short* __restrict__ B2lo,
    const float* __restrict__ bias, float* __restrict__ C, int M) {
    constexpr int LDAS = 40;  // bf16 elems per LDS row (+8 pad -> 2-way-free banks)
    __shared__ __align__(16) unsigned short Ah[128 * LDAS];
    __shared__ __align__(16) unsigned short Al[128 * LDAS];
    __shared__ __align__(16) unsigned short Bh[128 * LDAS];
    __shared__ __align__(16) unsigned short Bl[128 * LDAS];

    const int tid  = threadIdx.x;
    const int lane = tid & 63;
    const int wave = tid >> 6;
    const int wm   = (wave & 1) * 64;
    const int wn   = (wave >> 1) * 64;
    const int m0   = blockIdx.x * 128;
    const int n0   = blockIdx.y * 128;
    const int lrow  = tid >> 1;          // staging row 0..127
    const int lhalf = (tid & 1) * 16;    // staging k offset 0/16
    const int frow = lane & 15;          // fragment row within 16-tile
    const int fk   = (lane >> 4) * 8;    // fragment k offset

    floatx4 acc[4][4] = {};

    for (int k0 = 0; k0 < K1 + K2; k0 += 32) {
        const float* Ap; const unsigned short* Bhp; const unsigned short* Blp;
        int kk, lda;
        if (K2 == 0 || k0 < K1) { Ap = A1; Bhp = B1hi; Blp = B1lo; kk = k0;      lda = K1; }
        else                    { Ap = A2; Bhp = B2hi; Blp = B2lo; kk = k0 - K1; lda = K2; }

        // global loads
        int arow = m0 + lrow; if (arow >= M) arow = M - 1;
        const float* ap = Ap + (size_t)arow * lda + (kk + lhalf);
        float4 t0 = *(const float4*)(ap + 0);
        float4 t1 = *(const float4*)(ap + 4);
        float4 t2 = *(const float4*)(ap + 8);
        float4 t3 = *(const float4*)(ap + 12);
        float av[16] = {t0.x, t0.y, t0.z, t0.w, t1.x, t1.y, t1.z, t1.w,
                        t2.x, t2.y, t2.z, t2.w, t3.x, t3.y, t3.z, t3.w};
        const unsigned short* bhp = Bhp + (size_t)(n0 + lrow) * lda + (kk + lhalf);
        const unsigned short* blp = Blp + (size_t)(n0 + lrow) * lda + (kk + lhalf);
        ushort8 bh0 = *(const ushort8*)bhp;
        ushort8 bh1 = *(const ushort8*)(bhp + 8);
        ushort8 bl0 = *(const ushort8*)blp;
        ushort8 bl1 = *(const ushort8*)(blp + 8);

        __syncthreads();  // previous iteration's fragment reads done

        cvt_store8(&Ah[lrow * LDAS + lhalf + 0], &Al[lrow * LDAS + lhalf + 0], av + 0);
        cvt_store8(&Ah[lrow * LDAS + lhalf + 8], &Al[lrow * LDAS + lhalf + 8], av + 8);
        *(ushort8*)&Bh[lrow * LDAS + lhalf + 0] = bh0;
        *(ushort8*)&Bh[lrow * LDAS + lhalf + 8] = bh1;
        *(ushort8*)&Bl[lrow * LDAS + lhalf + 0] = bl0;
        *(ushort8*)&Bl[lrow * LDAS + lhalf + 8] = bl1;

        __syncthreads();

        short8 ahf[4], alf[4], bhf[4], blf[4];
#pragma unroll
        for (int t = 0; t < 4; t++) {
            int ar = (wm + t * 16 + frow) * LDAS + fk;
            ahf[t] = *(const short8*)&Ah[ar];
            alf[t] = *(const short8*)&Al[ar];
            int br = (wn + t * 16 + frow) * LDAS + fk;
            bhf[t] = *(const short8*)&Bh[br];
            blf[t] = *(const short8*)&Bl[br];
        }
#pragma unroll
        for (int i = 0; i < 4; i++) {
#pragma unroll
            for (int j = 0; j < 4; j++) {
                acc[i][j] = __builtin_amdgcn_mfma_f32_16x16x32_bf16(ahf[i], bhf[j], acc[i][j], 0, 0, 0);
                acc[i][j] = __builtin_amdgcn_mfma_f32_16x16x32_bf16(ahf[i], blf[j], acc[i][j], 0, 0, 0);
                acc[i][j] = __builtin_amdgcn_mfma_f32_16x16x32_bf16(alf[i], bhf[j], acc[i][j], 0, 0, 0);
            }
        }
    }

    // epilogue: C/D layout col=lane&15, row=(lane>>4)*4+reg
    const int col  = lane & 15;
    const int quad = lane >> 4;
#pragma unroll
    for (int j = 0; j < 4; j++) {
        int c = n0 + wn + j * 16 + col;
        float bj = bias ? bias[c] : 0.0f;
#pragma unroll
        for (int i = 0; i < 4; i++) {
            int rbase = m0 + wm + i * 16 + quad * 4;
#pragma unroll
            for (int r = 0; r < 4; r++) {
                int row = rbase + r;
                if (row < M) {
                    float v = acc[i][j][r] + bj;
                    if (RELU) v = fmaxf(v, 0.0f);
                    C[(size_t)row * 256 + c] = v;
                }
            }
        }
    }
}

// ---------------- Fused attention + output projection ----------------

__global__ __launch_bounds__(256) void attn_out_kernel(
    const float* __restrict__ h, const float* __restrict__ h2,
    const float* __restrict__ q1, const float* __restrict__ q2,
    const float* __restrict__ Wout, const float* __restrict__ bout,
    float* __restrict__ out, int Bn) {
    int w = threadIdx.x >> 6, lane = threadIdx.x & 63;
    int row = blockIdx.x * 4 + w;
    __shared__ __align__(16) float cbuf[4][260];
    if (row < Bn) {
        const float4 a = *(const float4*)(h  + (size_t)row * HID + lane * 4);
        const float4 p = *(const float4*)(q1 + (size_t)row * HID + lane * 4);
        const float4 b = *(const float4*)(h2 + (size_t)row * HID + lane * 4);
        const float4 q = *(const float4*)(q2 + (size_t)row * HID + lane * 4);
        float s0 = a.x * p.x + a.y * p.y + a.z * p.z + a.w * p.w;
        float s1 = b.x * q.x + b.y * q.y + b.z * q.z + b.w * q.w;
        for (int o = 32; o > 0; o >>= 1) {
            s0 += __shfl_xor(s0, o);
            s1 += __shfl_xor(s1, o);
        }
        float m  = fmaxf(s0, s1);
        float e0 = __expf(s0 - m), e1 = __expf(s1 - m);
        float inv = 1.0f / (e0 + e1);
        float a0 = e0 * inv, a1 = e1 * inv;
        float4 cv;
        cv.x = a0 * a.x + a1 * b.x; cv.y = a0 * a.y + a1 * b.y;
        cv.z = a0 * a.z + a1 * b.z; cv.w = a0 * a.w + a1 * b.w;
        *(float4*)&cbuf[w][lane * 4] = cv;
    }
    __syncthreads();
    int t = threadIdx.x;
    if (t < 4 * NCLS) {
        int r = t / NCLS, j = t % NCLS;
        int orow = blockIdx.x * 4 + r;
        if (orow < Bn) {
            float acc = bout[j];
#pragma unroll 8
            for (int k = 0; k < HID; k++) acc += cbuf[r][k] * Wout[k * NCLS + j];
            out[(size_t)orow * NCLS + j] = acc;
        }
    }
}

}  // namespace

extern "C" void kernel_launch(void* const* d_in, const int* in_sizes, int n_in,
                              void* d_out, int out_size, void* d_ws, size_t ws_size,
                              hipStream_t stream) {
    const float* x    = (const float*)d_in[0];
    const int*   src0 = (const int*)d_in[1];
    const int*   dst0 = (const int*)d_in[2];
    const int*   src1 = (const int*)d_in[3];
    const int*   dst1 = (const int*)d_in[4];
    const float* W1l  = (const float*)d_in[5];
    const float* b1   = (const float*)d_in[6];
    const float* W1r  = (const float*)d_in[7];
    const float* W2l  = (const float*)d_in[8];
    const float* b2   = (const float*)d_in[9];
    const float* W2r  = (const float*)d_in[10];
    const float* Wout = (const float*)d_in[11];
    const float* bout = (const float*)d_in[12];
    float* out = (float*)d_out;

    // ---- workspace carve-up (256B-aligned) ----
    char* ws = (char*)d_ws;
    size_t off = 0;
    auto alloc = [&](size_t bytes) {
        void* p = ws + off;
        off = (off + bytes + 255) & ~(size_t)255;
        return p;
    };
    int* cnt0  = (int*)alloc(N1i * sizeof(int));
    int* rp0   = (int*)alloc((N1i + 1) * sizeof(int));
    int* bsum0 = (int*)alloc(512 * sizeof(int));
    int* es0   = (int*)alloc(E0i * sizeof(int));
    int* cnt1  = (int*)alloc(Bni * sizeof(int));
    int* rp1   = (int*)alloc((Bni + 1) * sizeof(int));
    int* bsum1 = (int*)alloc(512 * sizeof(int));
    int* es1   = (int*)alloc(E1i * sizeof(int));
    // split/transposed weights: [256][K] bf16 hi/lo
    unsigned short* w1l_hi = (unsigned short*)alloc(256 * FIN * sizeof(unsigned short));
    unsigned short* w1l_lo = (unsigned short*)alloc(256 * FIN * sizeof(unsigned short));
    unsigned short* w1r_hi = (unsigned short*)alloc(256 * FIN * sizeof(unsigned short));
    unsigned short* w1r_lo = (unsigned short*)alloc(256 * FIN * sizeof(unsigned short));
    unsigned short* w2l_hi = (unsigned short*)alloc(256 * HID * sizeof(unsigned short));
    unsigned short* w2l_lo = (unsigned short*)alloc(256 * HID * sizeof(unsigned short));
    unsigned short* w2r_hi = (unsigned short*)alloc(256 * HID * sizeof(unsigned short));
    unsigned short* w2r_lo = (unsigned short*)alloc(256 * HID * sizeof(unsigned short));
    // agg region: agg0 (N1 x 128) during layer 1; then four B x 256 buffers.
    float* region = (float*)alloc((size_t)N1i * FIN * sizeof(float));
    float* h      = (float*)alloc((size_t)N1i * HID * sizeof(float));
    float* agg0 = region;
    float* hq1  = region;
    float* agg1 = region + (size_t)1 * Bni * HID;
    float* h2   = region + (size_t)2 * Bni * HID;
    float* h2q  = region + (size_t)3 * Bni * HID;

    // ---- weight split/transpose (independent of graph work) ----
    wtrans_kernel<<<(FIN * 256 + 255) / 256, 256, 0, stream>>>(W1l, FIN, w1l_hi, w1l_lo);
    wtrans_kernel<<<(FIN * 256 + 255) / 256, 256, 0, stream>>>(W1r, FIN, w1r_hi, w1r_lo);
    wtrans_kernel<<<(HID * 256 + 255) / 256, 256, 0, stream>>>(W2l, HID, w2l_hi, w2l_lo);
    wtrans_kernel<<<(HID * 256 + 255) / 256, 256, 0, stream>>>(W2r, HID, w2r_hi, w2r_lo);

    // ---- CSR build ----
    hipMemsetAsync(cnt0, 0, N1i * sizeof(int), stream);
    hipMemsetAsync(cnt1, 0, Bni * sizeof(int), stream);
    hist_kernel<<<(E0i + 255) / 256, 256, 0, stream>>>(dst0, E0i, cnt0);
    hist_kernel<<<(E1i + 255) / 256, 256, 0, stream>>>(dst1, E1i, cnt1);

    int nb0 = (N1i + 255) / 256, nb1 = (Bni + 255) / 256;
    partial_sum_kernel<<<nb0, 256, 0, stream>>>(cnt0, N1i, bsum0);
    scan_bsum_par_kernel<<<1, 512, 0, stream>>>(bsum0, nb0, rp0 + N1i);
    scan_final_kernel<<<nb0, 256, 0, stream>>>(cnt0, N1i, bsum0, rp0);
    copy_int_kernel<<<(N1i + 255) / 256, 256, 0, stream>>>(rp0, N1i, cnt0);
    scatter_kernel<<<(E0i + 255) / 256, 256, 0, stream>>>(src0, dst0, E0i, cnt0, es0);

    partial_sum_kernel<<<nb1, 256, 0, stream>>>(cnt1, Bni, bsum1);
    scan_bsum_par_kernel<<<1, 512, 0, stream>>>(bsum1, nb1, rp1 + Bni);
    scan_final_kernel<<<nb1, 256, 0, stream>>>(cnt1, Bni, bsum1, rp1);
    copy_int_kernel<<<(Bni + 255) / 256, 256, 0, stream>>>(rp1, Bni, cnt1);
    scatter_kernel<<<(E1i + 255) / 256, 256, 0, stream>>>(src1, dst1, E1i, cnt1, es1);

    // ---- layer 1 ----
    agg_mean128_kernel<<<(N1i + 3) / 4, 256, 0, stream>>>(x, rp0, es0, agg0, N1i);
    {
        dim3 g((N1i + 127) / 128, 2);
        // h = relu(agg0 @ W1l + x[:N1] @ W1r + b1)
        gemm_mfma_kernel<128, 128, true><<<g, 256, 0, stream>>>(
            agg0, x, w1l_hi, w1l_lo, w1r_hi, w1r_lo, b1, h, N1i);
    }
    {
        dim3 g((Bni + 127) / 128, 2);
        // hq1 = relu(x[:B] @ W1r)   (agg0 region is dead now)
        gemm_mfma_kernel<128, 0, true><<<g, 256, 0, stream>>>(
            x, nullptr, w1r_hi, w1r_lo, nullptr, nullptr, nullptr, hq1, Bni);
    }

    // ---- layer 2 ----
    agg_mean256_kernel<<<(Bni + 3) / 4, 256, 0, stream>>>(h, rp1, es1, agg1, Bni);
    {
        dim3 g((Bni + 127) / 128, 2);
        // h2 = relu(agg1 @ W2l + h[:B] @ W2r + b2)
        gemm_mfma_kernel<256, 256, true><<<g, 256, 0, stream>>>(
            agg1, h, w2l_hi, w2l_lo, w2r_hi, w2r_lo, b2, h2, Bni);
        // h2q = relu(hq1 @ W2r)
        gemm_mfma_kernel<256, 0, true><<<g, 256, 0, stream>>>(
            hq1, nullptr, w2r_hi, w2r_lo, nullptr, nullptr, nullptr, h2q, Bni);
    }

    // ---- attention + output projection ----
    attn_out_kernel<<<(Bni + 3) / 4, 256, 0, stream>>>(h, h2, hq1, h2q, Wout, bout, out, Bni);
}

// Round 3
// 745.294 us; speedup vs baseline: 1.3323x; 1.1093x over previous
//
#include <hip/hip_runtime.h>
#include <cstddef>

// TwinSAGE: 2-layer GraphSAGE (mean aggr) + twin query path + 2-way layer
// attention + output projection.
// Round 3: MLP-unrolled gather aggregation (shfl-broadcast edge indices,
// 4 outstanding gathers). GEMMs unchanged from round 2 (split-bf16 MFMA).

namespace {

constexpr int N1i  = 100000;
constexpr int Bni  = 10000;
constexpr int E0i  = 1000000;
constexpr int E1i  = 100000;
constexpr int FIN  = 128;
constexpr int HID  = 256;
constexpr int NCLS = 40;

typedef __attribute__((ext_vector_type(8))) short short8;
typedef __attribute__((ext_vector_type(8))) unsigned short ushort8;
typedef __attribute__((ext_vector_type(4))) float floatx4;

// ---------------- CSR build ----------------

__global__ void hist_kernel(const int* __restrict__ dst, int n, int* __restrict__ cnt) {
    int i = blockIdx.x * blockDim.x + threadIdx.x;
    if (i < n) atomicAdd(&cnt[dst[i]], 1);
}

__global__ void partial_sum_kernel(const int* __restrict__ cnt, int n, int* __restrict__ bsum) {
    __shared__ int s[256];
    int i = blockIdx.x * 256 + threadIdx.x;
    s[threadIdx.x] = (i < n) ? cnt[i] : 0;
    __syncthreads();
    for (int o = 128; o > 0; o >>= 1) {
        if (threadIdx.x < o) s[threadIdx.x] += s[threadIdx.x + o];
        __syncthreads();
    }
    if (threadIdx.x == 0) bsum[blockIdx.x] = s[0];
}

// Parallel single-block exclusive scan of bsum (nb <= 512).
__global__ void scan_bsum_par_kernel(int* __restrict__ bsum, int nb, int* __restrict__ total_out) {
    __shared__ int s[512];
    int t = threadIdx.x;
    int v = (t < nb) ? bsum[t] : 0;
    s[t] = v;
    __syncthreads();
    for (int o = 1; o < 512; o <<= 1) {
        int u = (t >= o) ? s[t - o] : 0;
        __syncthreads();
        s[t] += u;
        __syncthreads();
    }
    if (t < nb) bsum[t] = s[t] - v;   // exclusive
    if (t == 511) *total_out = s[511];
}

__global__ void scan_final_kernel(const int* __restrict__ cnt, int n,
                                  const int* __restrict__ bsum, int* __restrict__ row_ptr) {
    __shared__ int s[256];
    int t = threadIdx.x;
    int i = blockIdx.x * 256 + t;
    int v = (i < n) ? cnt[i] : 0;
    s[t] = v;
    __syncthreads();
    for (int o = 1; o < 256; o <<= 1) {
        int u = (t >= o) ? s[t - o] : 0;
        __syncthreads();
        s[t] += u;
        __syncthreads();
    }
    if (i < n) row_ptr[i] = bsum[blockIdx.x] + s[t] - v;  // exclusive
}

__global__ void copy_int_kernel(const int* __restrict__ a, int n, int* __restrict__ b) {
    int i = blockIdx.x * blockDim.x + threadIdx.x;
    if (i < n) b[i] = a[i];
}

__global__ void scatter_kernel(const int* __restrict__ src, const int* __restrict__ dst, int n,
                               int* __restrict__ cursor, int* __restrict__ es) {
    int i = blockIdx.x * blockDim.x + threadIdx.x;
    if (i < n) {
        int p = atomicAdd(&cursor[dst[i]], 1);
        es[p] = src[i];
    }
}

// ---------------- Mean aggregation (one wave per target, MLP-unrolled) ----
// Edge indices for up to 64 edges are fetched with ONE coalesced load into a
// lane register, then shfl-broadcast; gathers issue 4-at-a-time so 4 vmem
// loads are outstanding before the first accumulate (fixes round-2's
// latency-bound 1.6 TB/s: VALUBusy 9%, hbm 20%).

__global__ __launch_bounds__(256) void agg_mean128_kernel(
    const float* __restrict__ x, const int* __restrict__ rp,
    const int* __restrict__ es, float* __restrict__ out, int ntgt) {
    int tgt  = blockIdx.x * 4 + (threadIdx.x >> 6);
    int lane = threadIdx.x & 63;
    if (tgt >= ntgt) return;
    int b = rp[tgt], e = rp[tgt + 1];
    int d = e - b;
    float ax = 0.f, ay = 0.f;
    const float* xp = x + lane * 2;
    for (int base = 0; base < d; base += 64) {
        int rem = d - base; if (rem > 64) rem = 64;
        int li  = lane < rem ? lane : rem - 1;
        int idx = es[b + base + li];            // one coalesced load / 64 edges
        int j = 0;
        for (; j + 4 <= rem; j += 4) {
            int i0 = __shfl(idx, j + 0), i1 = __shfl(idx, j + 1);
            int i2 = __shfl(idx, j + 2), i3 = __shfl(idx, j + 3);
            float2 v0 = *(const float2*)(xp + (size_t)i0 * FIN);
            float2 v1 = *(const float2*)(xp + (size_t)i1 * FIN);
            float2 v2 = *(const float2*)(xp + (size_t)i2 * FIN);
            float2 v3 = *(const float2*)(xp + (size_t)i3 * FIN);
            ax += v0.x + v1.x + v2.x + v3.x;
            ay += v0.y + v1.y + v2.y + v3.y;
        }
        for (; j < rem; j++) {
            int i0 = __shfl(idx, j);
            float2 v0 = *(const float2*)(xp + (size_t)i0 * FIN);
            ax += v0.x; ay += v0.y;
        }
    }
    float inv = 1.0f / fmaxf((float)d, 1.0f);
    float2 r; r.x = ax * inv; r.y = ay * inv;
    *(float2*)(out + (size_t)tgt * FIN + lane * 2) = r;
}

__global__ __launch_bounds__(256) void agg_mean256_kernel(
    const float* __restrict__ h, const int* __restrict__ rp,
    const int* __restrict__ es, float* __restrict__ out, int ntgt) {
    int tgt  = blockIdx.x * 4 + (threadIdx.x >> 6);
    int lane = threadIdx.x & 63;
    if (tgt >= ntgt) return;
    int b = rp[tgt], e = rp[tgt + 1];
    int d = e - b;
    float4 acc = {0.f, 0.f, 0.f, 0.f};
    const float* hp = h + lane * 4;
    for (int base = 0; base < d; base += 64) {
        int rem = d - base; if (rem > 64) rem = 64;
        int li  = lane < rem ? lane : rem - 1;
        int idx = es[b + base + li];
        int j = 0;
        for (; j + 4 <= rem; j += 4) {
            int i0 = __shfl(idx, j + 0), i1 = __shfl(idx, j + 1);
            int i2 = __shfl(idx, j + 2), i3 = __shfl(idx, j + 3);
            float4 v0 = *(const float4*)(hp + (size_t)i0 * HID);
            float4 v1 = *(const float4*)(hp + (size_t)i1 * HID);
            float4 v2 = *(const float4*)(hp + (size_t)i2 * HID);
            float4 v3 = *(const float4*)(hp + (size_t)i3 * HID);
            acc.x += v0.x + v1.x + v2.x + v3.x;
            acc.y += v0.y + v1.y + v2.y + v3.y;
            acc.z += v0.z + v1.z + v2.z + v3.z;
            acc.w += v0.w + v1.w + v2.w + v3.w;
        }
        for (; j < rem; j++) {
            int i0 = __shfl(idx, j);
            float4 v0 = *(const float4*)(hp + (size_t)i0 * HID);
            acc.x += v0.x; acc.y += v0.y; acc.z += v0.z; acc.w += v0.w;
        }
    }
    float inv = 1.0f / fmaxf((float)d, 1.0f);
    float4 r; r.x = acc.x * inv; r.y = acc.y * inv; r.z = acc.z * inv; r.w = acc.w * inv;
    *(float4*)(out + (size_t)tgt * HID + lane * 4) = r;
}

// ---------------- weight transpose + bf16 hi/lo split ----------------

__device__ inline unsigned short bf16_rne_u(unsigned u) {
    unsigned r = u + 0x7fffu + ((u >> 16) & 1u);
    return (unsigned short)(r >> 16);
}

__global__ void wtrans_kernel(const float* __restrict__ W, int K,
                              unsigned short* __restrict__ hiT,
                              unsigned short* __restrict__ loT) {
    int e = blockIdx.x * blockDim.x + threadIdx.x;
    if (e >= K * 256) return;
    int k = e >> 8, n = e & 255;
    float f = W[e];
    unsigned short hs = bf16_rne_u(__float_as_uint(f));
    float lo = f - __uint_as_float((unsigned)hs << 16);
    unsigned short ls = bf16_rne_u(__float_as_uint(lo));
    hiT[n * K + k] = hs;
    loT[n * K + k] = ls;
}

// ---------------- split-bf16 MFMA GEMM ----------------
// C[M x 256] = act(A1@B1 + A2@B2 + bias), A fp32 row-major (stride = K),
// B pre-split/transposed bf16 hi/lo [256][K].
// 3-term split: Ahi*Bhi + Ahi*Blo + Alo*Bhi (error ~2^-17 rel).
// Block 128x128, 4 waves, wave = 4x4 tiles of mfma_f32_16x16x32_bf16, BK=32.

__device__ inline void cvt_store8(unsigned short* hi_dst, unsigned short* lo_dst,
                                  const float* v) {
    ushort8 h, l;
#pragma unroll
    for (int i = 0; i < 8; i++) {
        float f = v[i];
        unsigned short hs = bf16_rne_u(__float_as_uint(f));
        float lo = f - __uint_as_float((unsigned)hs << 16);
        h[i] = hs;
        l[i] = bf16_rne_u(__float_as_uint(lo));
    }
    *(ushort8*)hi_dst = h;
    *(ushort8*)lo_dst = l;
}

template <int K1, int K2, bool RELU>
__global__ __launch_bounds__(256, 2) void gemm_mfma_kernel(
    const float* __restrict__ A1, const float* __restrict__ A2,
    const unsigned short* __restrict__ B1hi, const unsigned short* __restrict__ B1lo,
    const unsigned short* __restrict__ B2hi, const unsigned short* __restrict__ B2lo,
    const float* __restrict__ bias, float* __restrict__ C, int M) {
    constexpr int LDAS = 40;  // bf16 elems per LDS row (+8 pad)
    __shared__ __align__(16) unsigned short Ah[128 * LDAS];
    __shared__ __align__(16) unsigned short Al[128 * LDAS];
    __shared__ __align__(16) unsigned short Bh[128 * LDAS];
    __shared__ __align__(16) unsigned short Bl[128 * LDAS];

    const int tid  = threadIdx.x;
    const int lane = tid & 63;
    const int wave = tid >> 6;
    const int wm   = (wave & 1) * 64;
    const int wn   = (wave >> 1) * 64;
    const int m0   = blockIdx.x * 128;
    const int n0   = blockIdx.y * 128;
    const int lrow  = tid >> 1;
    const int lhalf = (tid & 1) * 16;
    const int frow = lane & 15;
    const int fk   = (lane >> 4) * 8;

    floatx4 acc[4][4] = {};

    for (int k0 = 0; k0 < K1 + K2; k0 += 32) {
        const float* Ap; const unsigned short* Bhp; const unsigned short* Blp;
        int kk, lda;
        if (K2 == 0 || k0 < K1) { Ap = A1; Bhp = B1hi; Blp = B1lo; kk = k0;      lda = K1; }
        else                    { Ap = A2; Bhp = B2hi; Blp = B2lo; kk = k0 - K1; lda = K2; }

        int arow = m0 + lrow; if (arow >= M) arow = M - 1;
        const float* ap = Ap + (size_t)arow * lda + (kk + lhalf);
        float4 t0 = *(const float4*)(ap + 0);
        float4 t1 = *(const float4*)(ap + 4);
        float4 t2 = *(const float4*)(ap + 8);
        float4 t3 = *(const float4*)(ap + 12);
        float av[16] = {t0.x, t0.y, t0.z, t0.w, t1.x, t1.y, t1.z, t1.w,
                        t2.x, t2.y, t2.z, t2.w, t3.x, t3.y, t3.z, t3.w};
        const unsigned short* bhp = Bhp + (size_t)(n0 + lrow) * lda + (kk + lhalf);
        const unsigned short* blp = Blp + (size_t)(n0 + lrow) * lda + (kk + lhalf);
        ushort8 bh0 = *(const ushort8*)bhp;
        ushort8 bh1 = *(const ushort8*)(bhp + 8);
        ushort8 bl0 = *(const ushort8*)blp;
        ushort8 bl1 = *(const ushort8*)(blp + 8);

        __syncthreads();

        cvt_store8(&Ah[lrow * LDAS + lhalf + 0], &Al[lrow * LDAS + lhalf + 0], av + 0);
        cvt_store8(&Ah[lrow * LDAS + lhalf + 8], &Al[lrow * LDAS + lhalf + 8], av + 8);
        *(ushort8*)&Bh[lrow * LDAS + lhalf + 0] = bh0;
        *(ushort8*)&Bh[lrow * LDAS + lhalf + 8] = bh1;
        *(ushort8*)&Bl[lrow * LDAS + lhalf + 0] = bl0;
        *(ushort8*)&Bl[lrow * LDAS + lhalf + 8] = bl1;

        __syncthreads();

        short8 ahf[4], alf[4], bhf[4], blf[4];
#pragma unroll
        for (int t = 0; t < 4; t++) {
            int ar = (wm + t * 16 + frow) * LDAS + fk;
            ahf[t] = *(const short8*)&Ah[ar];
            alf[t] = *(const short8*)&Al[ar];
            int br = (wn + t * 16 + frow) * LDAS + fk;
            bhf[t] = *(const short8*)&Bh[br];
            blf[t] = *(const short8*)&Bl[br];
        }
#pragma unroll
        for (int i = 0; i < 4; i++) {
#pragma unroll
            for (int j = 0; j < 4; j++) {
                acc[i][j] = __builtin_amdgcn_mfma_f32_16x16x32_bf16(ahf[i], bhf[j], acc[i][j], 0, 0, 0);
                acc[i][j] = __builtin_amdgcn_mfma_f32_16x16x32_bf16(ahf[i], blf[j], acc[i][j], 0, 0, 0);
                acc[i][j] = __builtin_amdgcn_mfma_f32_16x16x32_bf16(alf[i], bhf[j], acc[i][j], 0, 0, 0);
            }
        }
    }

    const int col  = lane & 15;
    const int quad = lane >> 4;
#pragma unroll
    for (int j = 0; j < 4; j++) {
        int c = n0 + wn + j * 16 + col;
        float bj = bias ? bias[c] : 0.0f;
#pragma unroll
        for (int i = 0; i < 4; i++) {
            int rbase = m0 + wm + i * 16 + quad * 4;
#pragma unroll
            for (int r = 0; r < 4; r++) {
                int row = rbase + r;
                if (row < M) {
                    float v = acc[i][j][r] + bj;
                    if (RELU) v = fmaxf(v, 0.0f);
                    C[(size_t)row * 256 + c] = v;
                }
            }
        }
    }
}

// ---------------- Fused attention + output projection ----------------

__global__ __launch_bounds__(256) void attn_out_kernel(
    const float* __restrict__ h, const float* __restrict__ h2,
    const float* __restrict__ q1, const float* __restrict__ q2,
    const float* __restrict__ Wout, const float* __restrict__ bout,
    float* __restrict__ out, int Bn) {
    int w = threadIdx.x >> 6, lane = threadIdx.x & 63;
    int row = blockIdx.x * 4 + w;
    __shared__ __align__(16) float cbuf[4][260];
    if (row < Bn) {
        const float4 a = *(const float4*)(h  + (size_t)row * HID + lane * 4);
        const float4 p = *(const float4*)(q1 + (size_t)row * HID + lane * 4);
        const float4 b = *(const float4*)(h2 + (size_t)row * HID + lane * 4);
        const float4 q = *(const float4*)(q2 + (size_t)row * HID + lane * 4);
        float s0 = a.x * p.x + a.y * p.y + a.z * p.z + a.w * p.w;
        float s1 = b.x * q.x + b.y * q.y + b.z * q.z + b.w * q.w;
        for (int o = 32; o > 0; o >>= 1) {
            s0 += __shfl_xor(s0, o);
            s1 += __shfl_xor(s1, o);
        }
        float m  = fmaxf(s0, s1);
        float e0 = __expf(s0 - m), e1 = __expf(s1 - m);
        float inv = 1.0f / (e0 + e1);
        float a0 = e0 * inv, a1 = e1 * inv;
        float4 cv;
        cv.x = a0 * a.x + a1 * b.x; cv.y = a0 * a.y + a1 * b.y;
        cv.z = a0 * a.z + a1 * b.z; cv.w = a0 * a.w + a1 * b.w;
        *(float4*)&cbuf[w][lane * 4] = cv;
    }
    __syncthreads();
    int t = threadIdx.x;
    if (t < 4 * NCLS) {
        int r = t / NCLS, j = t % NCLS;
        int orow = blockIdx.x * 4 + r;
        if (orow < Bn) {
            float acc = bout[j];
#pragma unroll 8
            for (int k = 0; k < HID; k++) acc += cbuf[r][k] * Wout[k * NCLS + j];
            out[(size_t)orow * NCLS + j] = acc;
        }
    }
}

}  // namespace

extern "C" void kernel_launch(void* const* d_in, const int* in_sizes, int n_in,
                              void* d_out, int out_size, void* d_ws, size_t ws_size,
                              hipStream_t stream) {
    const float* x    = (const float*)d_in[0];
    const int*   src0 = (const int*)d_in[1];
    const int*   dst0 = (const int*)d_in[2];
    const int*   src1 = (const int*)d_in[3];
    const int*   dst1 = (const int*)d_in[4];
    const float* W1l  = (const float*)d_in[5];
    const float* b1   = (const float*)d_in[6];
    const float* W1r  = (const float*)d_in[7];
    const float* W2l  = (const float*)d_in[8];
    const float* b2   = (const float*)d_in[9];
    const float* W2r  = (const float*)d_in[10];
    const float* Wout = (const float*)d_in[11];
    const float* bout = (const float*)d_in[12];
    float* out = (float*)d_out;

    // ---- workspace carve-up (256B-aligned) ----
    char* ws = (char*)d_ws;
    size_t off = 0;
    auto alloc = [&](size_t bytes) {
        void* p = ws + off;
        off = (off + bytes + 255) & ~(size_t)255;
        return p;
    };
    int* cnt0  = (int*)alloc(N1i * sizeof(int));
    int* rp0   = (int*)alloc((N1i + 1) * sizeof(int));
    int* bsum0 = (int*)alloc(512 * sizeof(int));
    int* es0   = (int*)alloc(E0i * sizeof(int));
    int* cnt1  = (int*)alloc(Bni * sizeof(int));
    int* rp1   = (int*)alloc((Bni + 1) * sizeof(int));
    int* bsum1 = (int*)alloc(512 * sizeof(int));
    int* es1   = (int*)alloc(E1i * sizeof(int));
    unsigned short* w1l_hi = (unsigned short*)alloc(256 * FIN * sizeof(unsigned short));
    unsigned short* w1l_lo = (unsigned short*)alloc(256 * FIN * sizeof(unsigned short));
    unsigned short* w1r_hi = (unsigned short*)alloc(256 * FIN * sizeof(unsigned short));
    unsigned short* w1r_lo = (unsigned short*)alloc(256 * FIN * sizeof(unsigned short));
    unsigned short* w2l_hi = (unsigned short*)alloc(256 * HID * sizeof(unsigned short));
    unsigned short* w2l_lo = (unsigned short*)alloc(256 * HID * sizeof(unsigned short));
    unsigned short* w2r_hi = (unsigned short*)alloc(256 * HID * sizeof(unsigned short));
    unsigned short* w2r_lo = (unsigned short*)alloc(256 * HID * sizeof(unsigned short));
    float* region = (float*)alloc((size_t)N1i * FIN * sizeof(float));
    float* h      = (float*)alloc((size_t)N1i * HID * sizeof(float));
    float* agg0 = region;
    float* hq1  = region;
    float* agg1 = region + (size_t)1 * Bni * HID;
    float* h2   = region + (size_t)2 * Bni * HID;
    float* h2q  = region + (size_t)3 * Bni * HID;

    // ---- weight split/transpose ----
    wtrans_kernel<<<(FIN * 256 + 255) / 256, 256, 0, stream>>>(W1l, FIN, w1l_hi, w1l_lo);
    wtrans_kernel<<<(FIN * 256 + 255) / 256, 256, 0, stream>>>(W1r, FIN, w1r_hi, w1r_lo);
    wtrans_kernel<<<(HID * 256 + 255) / 256, 256, 0, stream>>>(W2l, HID, w2l_hi, w2l_lo);
    wtrans_kernel<<<(HID * 256 + 255) / 256, 256, 0, stream>>>(W2r, HID, w2r_hi, w2r_lo);

    // ---- CSR build ----
    hipMemsetAsync(cnt0, 0, N1i * sizeof(int), stream);
    hipMemsetAsync(cnt1, 0, Bni * sizeof(int), stream);
    hist_kernel<<<(E0i + 255) / 256, 256, 0, stream>>>(dst0, E0i, cnt0);
    hist_kernel<<<(E1i + 255) / 256, 256, 0, stream>>>(dst1, E1i, cnt1);

    int nb0 = (N1i + 255) / 256, nb1 = (Bni + 255) / 256;
    partial_sum_kernel<<<nb0, 256, 0, stream>>>(cnt0, N1i, bsum0);
    scan_bsum_par_kernel<<<1, 512, 0, stream>>>(bsum0, nb0, rp0 + N1i);
    scan_final_kernel<<<nb0, 256, 0, stream>>>(cnt0, N1i, bsum0, rp0);
    copy_int_kernel<<<(N1i + 255) / 256, 256, 0, stream>>>(rp0, N1i, cnt0);
    scatter_kernel<<<(E0i + 255) / 256, 256, 0, stream>>>(src0, dst0, E0i, cnt0, es0);

    partial_sum_kernel<<<nb1, 256, 0, stream>>>(cnt1, Bni, bsum1);
    scan_bsum_par_kernel<<<1, 512, 0, stream>>>(bsum1, nb1, rp1 + Bni);
    scan_final_kernel<<<nb1, 256, 0, stream>>>(cnt1, Bni, bsum1, rp1);
    copy_int_kernel<<<(Bni + 255) / 256, 256, 0, stream>>>(rp1, Bni, cnt1);
    scatter_kernel<<<(E1i + 255) / 256, 256, 0, stream>>>(src1, dst1, E1i, cnt1, es1);

    // ---- layer 1 ----
    agg_mean128_kernel<<<(N1i + 3) / 4, 256, 0, stream>>>(x, rp0, es0, agg0, N1i);
    {
        dim3 g((N1i + 127) / 128, 2);
        gemm_mfma_kernel<128, 128, true><<<g, 256, 0, stream>>>(
            agg0, x, w1l_hi, w1l_lo, w1r_hi, w1r_lo, b1, h, N1i);
    }
    {
        dim3 g((Bni + 127) / 128, 2);
        gemm_mfma_kernel<128, 0, true><<<g, 256, 0, stream>>>(
            x, nullptr, w1r_hi, w1r_lo, nullptr, nullptr, nullptr, hq1, Bni);
    }

    // ---- layer 2 ----
    agg_mean256_kernel<<<(Bni + 3) / 4, 256, 0, stream>>>(h, rp1, es1, agg1, Bni);
    {
        dim3 g((Bni + 127) / 128, 2);
        gemm_mfma_kernel<256, 256, true><<<g, 256, 0, stream>>>(
            agg1, h, w2l_hi, w2l_lo, w2r_hi, w2r_lo, b2, h2, Bni);
        gemm_mfma_kernel<256, 0, true><<<g, 256, 0, stream>>>(
            hq1, nullptr, w2r_hi, w2r_lo, nullptr, nullptr, nullptr, h2q, Bni);
    }

    // ---- attention + output projection ----
    attn_out_kernel<<<(Bni + 3) / 4, 256, 0, stream>>>(h, h2, hq1, h2q, Wout, bout, out, Bni);
}